// Round 1
// baseline (312.642 us; speedup 1.0000x reference)
//
#include <hip/hip_runtime.h>

#define SS 128
#define RR 128
#define CC 128
#define EPSF 1e-14f

// acc[0]=sum CO, acc[1]=sum ds^2, acc[2]=sum dr^2, acc[3]=sum dc^2
__global__ __launch_bounds__(256) void scol_main(const float* __restrict__ L,
                                                 const float* __restrict__ U,
                                                 double* __restrict__ acc,
                                                 int B, int nvec) {
    const int SRC = SS * RR * CC;
    const int CV = CC / 4;

    float a_co = 0.f, a_ds = 0.f, a_dr = 0.f, a_dc = 0.f;

    for (int t = blockIdx.x * blockDim.x + threadIdx.x; t < nvec;
         t += gridDim.x * blockDim.x) {
        int c4 = t % CV;
        int r  = (t / CV) % RR;
        int s  = (t / (CV * RR)) % SS;
        int b  = t / (CV * RR * SS);
        int c  = c4 * 4;

        int pos    = ((s * RR) + r) * CC + c;          // within one channel plane
        int base_l = b * 3 * SRC + pos;
        int base_u = b * 9 * SRC + pos;

        // ---- argmax over 3 L channels, per c-position ----
        float4 l0 = *(const float4*)(L + base_l);
        float4 l1 = *(const float4*)(L + base_l + SRC);
        float4 l2 = *(const float4*)(L + base_l + 2 * SRC);
        float L0[4] = {l0.x, l0.y, l0.z, l0.w};
        float L1[4] = {l1.x, l1.y, l1.z, l1.w};
        float L2[4] = {l2.x, l2.y, l2.z, l2.w};
        int idx[4];
#pragma unroll
        for (int j = 0; j < 4; ++j) {
            int id = 0;
            float best = L0[j];
            if (L1[j] > best) { best = L1[j]; id = 1; }
            if (L2[j] > best) { best = L2[j]; id = 2; }
            idx[j] = id;
        }

        float am[3][4];
#pragma unroll
        for (int g = 0; g < 3; ++g)
#pragma unroll
            for (int j = 0; j < 4; ++j) am[g][j] = 0.f;

        bool has_c = (c4 < CV - 1);
        bool has_r = (r < RR - 1);
        bool has_s = (s < SS - 1);

#pragma unroll
        for (int ch = 0; ch < 9; ++ch) {
            int o = base_u + ch * SRC;
            float4 u = *(const float4*)(U + o);
            float uu[4] = {u.x, u.y, u.z, u.w};

            int g = ch / 3, m = ch % 3;
#pragma unroll
            for (int j = 0; j < 4; ++j)
                if (idx[j] == m) am[g][j] = fabsf(uu[j]);

            float d;
            d = u.y - u.x; a_dc += d * d;
            d = u.z - u.y; a_dc += d * d;
            d = u.w - u.z; a_dc += d * d;
            if (has_c) { float un = U[o + 4]; d = un - u.w; a_dc += d * d; }
            if (has_r) {
                float4 ur = *(const float4*)(U + o + CC);
                d = ur.x - u.x; a_dr += d * d;
                d = ur.y - u.y; a_dr += d * d;
                d = ur.z - u.z; a_dr += d * d;
                d = ur.w - u.w; a_dr += d * d;
            }
            if (has_s) {
                float4 us = *(const float4*)(U + o + RR * CC);
                d = us.x - u.x; a_ds += d * d;
                d = us.y - u.y; a_ds += d * d;
                d = us.z - u.z; a_ds += d * d;
                d = us.w - u.w; a_ds += d * d;
            }
        }

        // ---- CO per c-position ----
#pragma unroll
        for (int j = 0; j < 4; ++j) {
            float e1 = am[0][j], e2 = am[1][j], e3 = am[2][j];
            float den = e1 * e1 + e2 * e2 + e3 * e3;
            den = fmaxf(den, EPSF);
            float num = 0.5f * ((e1 - e2) * (e1 - e2) + (e2 - e3) * (e2 - e3) +
                                (e3 - e1) * (e3 - e1));
            a_co += sqrtf(num / den);
        }
    }

    // ---- wave reduce (64 lanes) ----
#pragma unroll
    for (int off = 32; off > 0; off >>= 1) {
        a_co += __shfl_down(a_co, off);
        a_ds += __shfl_down(a_ds, off);
        a_dr += __shfl_down(a_dr, off);
        a_dc += __shfl_down(a_dc, off);
    }

    __shared__ float s_co[4], s_ds[4], s_dr[4], s_dc[4];
    int wid = threadIdx.x >> 6;
    int lane = threadIdx.x & 63;
    if (lane == 0) {
        s_co[wid] = a_co; s_ds[wid] = a_ds;
        s_dr[wid] = a_dr; s_dc[wid] = a_dc;
    }
    __syncthreads();
    if (threadIdx.x == 0) {
        float t_co = 0.f, t_ds = 0.f, t_dr = 0.f, t_dc = 0.f;
        int nw = blockDim.x >> 6;
        for (int w = 0; w < nw; ++w) {
            t_co += s_co[w]; t_ds += s_ds[w];
            t_dr += s_dr[w]; t_dc += s_dc[w];
        }
        atomicAdd(&acc[0], (double)t_co);
        atomicAdd(&acc[1], (double)t_ds);
        atomicAdd(&acc[2], (double)t_dr);
        atomicAdd(&acc[3], (double)t_dc);
    }
}

__global__ void scol_final(const double* __restrict__ acc,
                           float* __restrict__ out, int B) {
    double nvox = (double)B * SS * RR * CC;
    double nds  = (double)B * (SS - 1) * RR * CC;
    double ndr  = (double)B * SS * (RR - 1) * CC;
    double ndc  = (double)B * SS * RR * (CC - 1);
    double res = 0.5 * (acc[0] / nvox + acc[1] / nds + acc[2] / ndr + acc[3] / ndc);
    out[0] = (float)res;
}

extern "C" void kernel_launch(void* const* d_in, const int* in_sizes, int n_in,
                              void* d_out, int out_size, void* d_ws, size_t ws_size,
                              hipStream_t stream) {
    const float* L = (const float*)d_in[0];
    const float* U = (const float*)d_in[1];
    float* out = (float*)d_out;

    int B = in_sizes[1] / (9 * SS * RR * CC);
    int nvec = B * SS * RR * (CC / 4);

    double* acc = (double*)d_ws;
    hipMemsetAsync(d_ws, 0, 4 * sizeof(double), stream);

    int threads = 256;
    int blocks = 1024;
    hipLaunchKernelGGL(scol_main, dim3(blocks), dim3(threads), 0, stream,
                       L, U, acc, B, nvec);
    hipLaunchKernelGGL(scol_final, dim3(1), dim3(1), 0, stream, acc, out, B);
}

// Round 2
// 252.844 us; speedup vs baseline: 1.2365x; 1.2365x over previous
//
#include <hip/hip_runtime.h>

#define SS 128
#define RR 128
#define CC 128
#define EPSF 1e-14f

// Each block writes one float4 partial: {sum CO, sum ds^2, sum dr^2, sum dc^2}
__global__ __launch_bounds__(256) void scol_main(const float* __restrict__ L,
                                                 const float* __restrict__ U,
                                                 float4* __restrict__ part,
                                                 int nvec) {
    const int SRC = SS * RR * CC;
    const int CV = CC / 4;

    float a_co = 0.f, a_ds = 0.f, a_dr = 0.f, a_dc = 0.f;

    int t = blockIdx.x * blockDim.x + threadIdx.x;
    if (t < nvec) {
        int c4 = t % CV;
        int r  = (t / CV) % RR;
        int s  = (t / (CV * RR)) % SS;
        int b  = t / (CV * RR * SS);
        int c  = c4 * 4;

        int pos    = ((s * RR) + r) * CC + c;
        int base_l = b * 3 * SRC + pos;
        int base_u = b * 9 * SRC + pos;

        // ---- argmax over 3 L channels ----
        float4 l0 = *(const float4*)(L + base_l);
        float4 l1 = *(const float4*)(L + base_l + SRC);
        float4 l2 = *(const float4*)(L + base_l + 2 * SRC);
        float L0[4] = {l0.x, l0.y, l0.z, l0.w};
        float L1[4] = {l1.x, l1.y, l1.z, l1.w};
        float L2[4] = {l2.x, l2.y, l2.z, l2.w};
        int idx[4];
#pragma unroll
        for (int j = 0; j < 4; ++j) {
            int id = 0;
            float best = L0[j];
            if (L1[j] > best) { best = L1[j]; id = 1; }
            if (L2[j] > best) { best = L2[j]; id = 2; }
            idx[j] = id;
        }

        float am[3][4];
#pragma unroll
        for (int g = 0; g < 3; ++g)
#pragma unroll
            for (int j = 0; j < 4; ++j) am[g][j] = 0.f;

        bool has_c = (c4 < CV - 1);
        bool has_r = (r < RR - 1);
        bool has_s = (s < SS - 1);

#pragma unroll
        for (int ch = 0; ch < 9; ++ch) {
            int o = base_u + ch * SRC;
            float4 u = *(const float4*)(U + o);
            float uu[4] = {u.x, u.y, u.z, u.w};

            int g = ch / 3, m = ch % 3;
#pragma unroll
            for (int j = 0; j < 4; ++j)
                if (idx[j] == m) am[g][j] = fabsf(uu[j]);

            float d;
            d = u.y - u.x; a_dc += d * d;
            d = u.z - u.y; a_dc += d * d;
            d = u.w - u.z; a_dc += d * d;
            if (has_c) { float un = U[o + 4]; d = un - u.w; a_dc += d * d; }
            if (has_r) {
                float4 ur = *(const float4*)(U + o + CC);
                d = ur.x - u.x; a_dr += d * d;
                d = ur.y - u.y; a_dr += d * d;
                d = ur.z - u.z; a_dr += d * d;
                d = ur.w - u.w; a_dr += d * d;
            }
            if (has_s) {
                float4 us = *(const float4*)(U + o + RR * CC);
                d = us.x - u.x; a_ds += d * d;
                d = us.y - u.y; a_ds += d * d;
                d = us.z - u.z; a_ds += d * d;
                d = us.w - u.w; a_ds += d * d;
            }
        }

        // ---- CO ----
#pragma unroll
        for (int j = 0; j < 4; ++j) {
            float e1 = am[0][j], e2 = am[1][j], e3 = am[2][j];
            float den = e1 * e1 + e2 * e2 + e3 * e3;
            den = fmaxf(den, EPSF);
            float num = 0.5f * ((e1 - e2) * (e1 - e2) + (e2 - e3) * (e2 - e3) +
                                (e3 - e1) * (e3 - e1));
            a_co += sqrtf(num / den);
        }
    }

    // ---- wave reduce (64 lanes) ----
#pragma unroll
    for (int off = 32; off > 0; off >>= 1) {
        a_co += __shfl_down(a_co, off);
        a_ds += __shfl_down(a_ds, off);
        a_dr += __shfl_down(a_dr, off);
        a_dc += __shfl_down(a_dc, off);
    }

    __shared__ float s_co[4], s_ds[4], s_dr[4], s_dc[4];
    int wid = threadIdx.x >> 6;
    int lane = threadIdx.x & 63;
    if (lane == 0) {
        s_co[wid] = a_co; s_ds[wid] = a_ds;
        s_dr[wid] = a_dr; s_dc[wid] = a_dc;
    }
    __syncthreads();
    if (threadIdx.x == 0) {
        float t_co = 0.f, t_ds = 0.f, t_dr = 0.f, t_dc = 0.f;
        for (int w = 0; w < 4; ++w) {
            t_co += s_co[w]; t_ds += s_ds[w];
            t_dr += s_dr[w]; t_dc += s_dc[w];
        }
        part[blockIdx.x] = make_float4(t_co, t_ds, t_dr, t_dc);
    }
}

// Single block: reduce nblk float4 partials in double, emit the scalar.
__global__ __launch_bounds__(256) void scol_final(const float4* __restrict__ part,
                                                  float* __restrict__ out,
                                                  int nblk, int B) {
    double d_co = 0., d_ds = 0., d_dr = 0., d_dc = 0.;
    for (int i = threadIdx.x; i < nblk; i += blockDim.x) {
        float4 p = part[i];
        d_co += (double)p.x; d_ds += (double)p.y;
        d_dr += (double)p.z; d_dc += (double)p.w;
    }
#pragma unroll
    for (int off = 32; off > 0; off >>= 1) {
        d_co += __shfl_down(d_co, off);
        d_ds += __shfl_down(d_ds, off);
        d_dr += __shfl_down(d_dr, off);
        d_dc += __shfl_down(d_dc, off);
    }
    __shared__ double sh[4][4];
    int wid = threadIdx.x >> 6;
    int lane = threadIdx.x & 63;
    if (lane == 0) {
        sh[wid][0] = d_co; sh[wid][1] = d_ds;
        sh[wid][2] = d_dr; sh[wid][3] = d_dc;
    }
    __syncthreads();
    if (threadIdx.x == 0) {
        double t_co = 0., t_ds = 0., t_dr = 0., t_dc = 0.;
        for (int w = 0; w < 4; ++w) {
            t_co += sh[w][0]; t_ds += sh[w][1];
            t_dr += sh[w][2]; t_dc += sh[w][3];
        }
        double nvox = (double)B * SS * RR * CC;
        double nds  = (double)B * (SS - 1) * RR * CC;
        double ndr  = (double)B * SS * (RR - 1) * CC;
        double ndc  = (double)B * SS * RR * (CC - 1);
        out[0] = (float)(0.5 * (t_co / nvox + t_ds / nds + t_dr / ndr + t_dc / ndc));
    }
}

extern "C" void kernel_launch(void* const* d_in, const int* in_sizes, int n_in,
                              void* d_out, int out_size, void* d_ws, size_t ws_size,
                              hipStream_t stream) {
    const float* L = (const float*)d_in[0];
    const float* U = (const float*)d_in[1];
    float* out = (float*)d_out;

    int B = in_sizes[1] / (9 * SS * RR * CC);
    int nvec = B * SS * RR * (CC / 4);

    int threads = 256;
    int blocks = (nvec + threads - 1) / threads;   // 4096 for B=2

    float4* part = (float4*)d_ws;

    hipLaunchKernelGGL(scol_main, dim3(blocks), dim3(threads), 0, stream,
                       L, U, part, nvec);
    hipLaunchKernelGGL(scol_final, dim3(1), dim3(threads), 0, stream,
                       part, out, blocks, B);
}

// Round 3
// 245.358 us; speedup vs baseline: 1.2742x; 1.0305x over previous
//
#include <hip/hip_runtime.h>

#define SS 128
#define RR 128
#define CC 128
#define EPSF 1e-14f

// Block = 256 threads = 8 rows x 32 float4-columns. One voxel-vector per thread.
// All loads unconditional & batched up front; boundaries handled by 0/1 weights.
__global__ __launch_bounds__(256, 2) void scol_main(const float* __restrict__ L,
                                                    const float* __restrict__ U,
                                                    float4* __restrict__ part) {
    const int SRC = SS * RR * CC;

    int tid = threadIdx.x;
    int c4  = tid & 31;
    int row = blockIdx.x * 8 + (tid >> 5);   // (b*S + s)*R + r over all batches
    int r   = row & (RR - 1);
    int sr  = row >> 7;                      // b*S + s
    int s   = sr & (SS - 1);
    int b   = sr >> 7;
    int c   = c4 << 2;

    int pos    = (row - b * (SS * RR)) * CC + c;   // (s*R + r)*C + c
    int base_l = b * 3 * SRC + pos;
    int base_u = b * 9 * SRC + pos;

    bool  hr = (r < RR - 1), hs = (s < SS - 1), hc = (c4 < 31);
    float wr = hr ? 1.f : 0.f;
    float ws = hs ? 1.f : 0.f;
    float wc = hc ? 1.f : 0.f;
    int offr = hr ? CC : 0;          // clamped: boundary re-loads self (L1 hit)
    int offs = hs ? RR * CC : 0;

    // ---------- batched load phase: 30 x global_load_dwordx4 ----------
    float4 l0 = *(const float4*)(L + base_l);
    float4 l1 = *(const float4*)(L + base_l + SRC);
    float4 l2 = *(const float4*)(L + base_l + 2 * SRC);

    float4 u[9], ur[9], us[9];
#pragma unroll
    for (int ch = 0; ch < 9; ++ch) {
        const float* p = U + base_u + ch * SRC;
        u[ch] = *(const float4*)(p);
    }
#pragma unroll
    for (int ch = 0; ch < 9; ++ch) {
        const float* p = U + base_u + ch * SRC;
        ur[ch] = *(const float4*)(p + offr);
        us[ch] = *(const float4*)(p + offs);
    }

    // ---------- compute phase ----------
    float L0[4] = {l0.x, l0.y, l0.z, l0.w};
    float L1[4] = {l1.x, l1.y, l1.z, l1.w};
    float L2[4] = {l2.x, l2.y, l2.z, l2.w};
    int idx[4];
#pragma unroll
    for (int j = 0; j < 4; ++j) {
        int id = 0;
        float best = L0[j];
        if (L1[j] > best) { best = L1[j]; id = 1; }
        if (L2[j] > best) { best = L2[j]; id = 2; }
        idx[j] = id;
    }

    float am[3][4];
#pragma unroll
    for (int g = 0; g < 3; ++g)
#pragma unroll
        for (int j = 0; j < 4; ++j) am[g][j] = 0.f;

    float a_dc = 0.f, t_dcb = 0.f, t_dr = 0.f, t_ds = 0.f;

#pragma unroll
    for (int ch = 0; ch < 9; ++ch) {
        float4 uu = u[ch];
        float uuv[4] = {uu.x, uu.y, uu.z, uu.w};
        int g = ch / 3, m = ch % 3;
#pragma unroll
        for (int j = 0; j < 4; ++j)
            if (idx[j] == m) am[g][j] = fabsf(uuv[j]);

        float d;
        d = uu.y - uu.x; a_dc += d * d;
        d = uu.z - uu.y; a_dc += d * d;
        d = uu.w - uu.z; a_dc += d * d;
        float un = __shfl_down(uu.x, 1);       // next float4's first elem
        d = un - uu.w; t_dcb += d * d;

        float4 R4 = ur[ch];
        d = R4.x - uu.x; t_dr += d * d;
        d = R4.y - uu.y; t_dr += d * d;
        d = R4.z - uu.z; t_dr += d * d;
        d = R4.w - uu.w; t_dr += d * d;

        float4 S4 = us[ch];
        d = S4.x - uu.x; t_ds += d * d;
        d = S4.y - uu.y; t_ds += d * d;
        d = S4.z - uu.z; t_ds += d * d;
        d = S4.w - uu.w; t_ds += d * d;
    }
    a_dc += wc * t_dcb;
    float a_dr = wr * t_dr;
    float a_ds = ws * t_ds;

    float a_co = 0.f;
#pragma unroll
    for (int j = 0; j < 4; ++j) {
        float e1 = am[0][j], e2 = am[1][j], e3 = am[2][j];
        float den = e1 * e1 + e2 * e2 + e3 * e3;
        den = fmaxf(den, EPSF);
        float num = 0.5f * ((e1 - e2) * (e1 - e2) + (e2 - e3) * (e2 - e3) +
                            (e3 - e1) * (e3 - e1));
        a_co += sqrtf(num / den);
    }

    // ---------- wave reduce (64 lanes) ----------
#pragma unroll
    for (int off = 32; off > 0; off >>= 1) {
        a_co += __shfl_down(a_co, off);
        a_ds += __shfl_down(a_ds, off);
        a_dr += __shfl_down(a_dr, off);
        a_dc += __shfl_down(a_dc, off);
    }

    __shared__ float s_co[4], s_ds[4], s_dr[4], s_dc[4];
    int wid  = threadIdx.x >> 6;
    int lane = threadIdx.x & 63;
    if (lane == 0) {
        s_co[wid] = a_co; s_ds[wid] = a_ds;
        s_dr[wid] = a_dr; s_dc[wid] = a_dc;
    }
    __syncthreads();
    if (threadIdx.x == 0) {
        float t_co = 0.f, t_s = 0.f, t_r = 0.f, t_c = 0.f;
        for (int w = 0; w < 4; ++w) {
            t_co += s_co[w]; t_s += s_ds[w];
            t_r += s_dr[w]; t_c += s_dc[w];
        }
        part[blockIdx.x] = make_float4(t_co, t_s, t_r, t_c);
    }
}

// Single block: reduce nblk float4 partials in double, emit the scalar.
__global__ __launch_bounds__(256) void scol_final(const float4* __restrict__ part,
                                                  float* __restrict__ out,
                                                  int nblk, int B) {
    double d_co = 0., d_ds = 0., d_dr = 0., d_dc = 0.;
    for (int i = threadIdx.x; i < nblk; i += blockDim.x) {
        float4 p = part[i];
        d_co += (double)p.x; d_ds += (double)p.y;
        d_dr += (double)p.z; d_dc += (double)p.w;
    }
#pragma unroll
    for (int off = 32; off > 0; off >>= 1) {
        d_co += __shfl_down(d_co, off);
        d_ds += __shfl_down(d_ds, off);
        d_dr += __shfl_down(d_dr, off);
        d_dc += __shfl_down(d_dc, off);
    }
    __shared__ double sh[4][4];
    int wid  = threadIdx.x >> 6;
    int lane = threadIdx.x & 63;
    if (lane == 0) {
        sh[wid][0] = d_co; sh[wid][1] = d_ds;
        sh[wid][2] = d_dr; sh[wid][3] = d_dc;
    }
    __syncthreads();
    if (threadIdx.x == 0) {
        double t_co = 0., t_ds = 0., t_dr = 0., t_dc = 0.;
        for (int w = 0; w < 4; ++w) {
            t_co += sh[w][0]; t_ds += sh[w][1];
            t_dr += sh[w][2]; t_dc += sh[w][3];
        }
        double nvox = (double)B * SS * RR * CC;
        double nds  = (double)B * (SS - 1) * RR * CC;
        double ndr  = (double)B * SS * (RR - 1) * CC;
        double ndc  = (double)B * SS * RR * (CC - 1);
        out[0] = (float)(0.5 * (t_co / nvox + t_ds / nds + t_dr / ndr + t_dc / ndc));
    }
}

extern "C" void kernel_launch(void* const* d_in, const int* in_sizes, int n_in,
                              void* d_out, int out_size, void* d_ws, size_t ws_size,
                              hipStream_t stream) {
    const float* L = (const float*)d_in[0];
    const float* U = (const float*)d_in[1];
    float* out = (float*)d_out;

    int B = in_sizes[1] / (9 * SS * RR * CC);
    int nrow = B * SS * RR;                 // total rows
    int blocks = nrow / 8;                  // 8 rows per block (4096 for B=2)

    float4* part = (float4*)d_ws;

    hipLaunchKernelGGL(scol_main, dim3(blocks), dim3(256), 0, stream,
                       L, U, part);
    hipLaunchKernelGGL(scol_final, dim3(1), dim3(256), 0, stream,
                       part, out, blocks, B);
}